// Round 7
// baseline (388.402 us; speedup 1.0000x reference)
//
#include <hip/hip_runtime.h>

#define NB 16           // B images
#define NP 16000        // proposals per image (= 250*64)
#define NG 256          // gt boxes per image
#define NM (NP + NG)    // proposals + gt = 16256 = 254*64
#define NSTRIP 254      // NM / 64
#define NS 512          // samples per image
#define NCLS 91
#define SL1_BETA (1.0f/9.0f)
#define LOSS_BLOCKS 512

// ---------------------------------------------------------------------------
// Kernel 1 (match): thread handles TWO rows (jA, jB=jA+256) so each GT's
// 2 LDS reads feed 2 predicate evaluations. Qualifier masks live in
// REGISTERS (8 u32 per side, all compile-time indexed). Exact predicate
// iou >= 0.5  <=>  3*inter >= ap+garea (fmaf single-rounding preserves sign).
// qcnt==0 -> negative; qcnt==1 -> argmax is that bit; qcnt>=2 (rare) ->
// exact cross-product argmax over set bits (ascending g = first-max tie
// rule). GT self-rows flow through the generic path. grid = (32, NB) x 256.
// ---------------------------------------------------------------------------
__global__ __launch_bounds__(256) void match_kernel(
    const float4* __restrict__ props4,        // [NB*NP]
    const float4* __restrict__ gt4,           // [NB*NG]
    const int*    __restrict__ gt_labels,     // [NB*NG]
    unsigned long long* __restrict__ posmask, // [NB*NSTRIP]
    unsigned int* __restrict__ posinfo)       // [NB*NM]
{
    __shared__ float4   gbox[NG];     // 4 KB
    __shared__ float    gar[NG];      // 1 KB
    __shared__ int      glab[NG];     // 1 KB

    const int b   = blockIdx.y;
    const int tid = threadIdx.x;

    {   // 256 threads load 256 gts
        const float4 v = gt4[(size_t)b * NG + tid];
        gbox[tid] = v;
        gar[tid]  = (v.z - v.x) * (v.w - v.y);
        glab[tid] = gt_labels[b * NG + tid];
    }
    __syncthreads();

    const int jA = blockIdx.x * 512 + tid;          // always < NM
    const int jB = jA + 256;                        // OOB only in last block
    const bool haveB = (jB < NM);                   // wave-uniform (128|64)

    const float4 pA = (jA < NP) ? props4[(size_t)b * NP + jA]
                                : gt4[(size_t)b * NG + (jA - NP)];
    float4 pB = make_float4(0.f, 0.f, 0.f, 0.f);    // dummy never qualifies
    if (haveB) pB = (jB < NP) ? props4[(size_t)b * NP + jB]
                              : gt4[(size_t)b * NG + (jB - NP)];
    const float apA = (pA.z - pA.x) * (pA.w - pA.y);
    const float apB = (pB.z - pB.x) * (pB.w - pB.y);

    unsigned qmA[8], qmB[8];
    int qcA = 0, qcB = 0, gfA = 0, gfB = 0;
    #pragma unroll
    for (int w = 0; w < 8; ++w) {
        unsigned mA = 0, mB = 0;
        #pragma unroll
        for (int t = 0; t < 32; ++t) {
            const int g = w * 32 + t;
            const float4 gb = gbox[g];
            const float  ga = gar[g];
            {   // row A
                float lx = fmaxf(gb.x, pA.x), ly = fmaxf(gb.y, pA.y);
                float rx = fminf(gb.z, pA.z), ry = fminf(gb.w, pA.w);
                float ww = fmaxf(rx - lx, 0.0f), hh = fmaxf(ry - ly, 0.0f);
                float inter = ww * hh;
                float tt = ga + apA;
                if (fmaf(inter, 3.0f, -tt) >= 0.0f) mA |= (1u << t);
            }
            {   // row B
                float lx = fmaxf(gb.x, pB.x), ly = fmaxf(gb.y, pB.y);
                float rx = fminf(gb.z, pB.z), ry = fminf(gb.w, pB.w);
                float ww = fmaxf(rx - lx, 0.0f), hh = fmaxf(ry - ly, 0.0f);
                float inter = ww * hh;
                float tt = ga + apB;
                if (fmaf(inter, 3.0f, -tt) >= 0.0f) mB |= (1u << t);
            }
        }
        qmA[w] = mA; qmB[w] = mB;
        if (qcA == 0 && mA) gfA = w * 32 + (__ffs(mA) - 1);
        if (qcB == 0 && mB) gfB = w * 32 + (__ffs(mB) - 1);
        qcA += __popc(mA);
        qcB += __popc(mB);
    }

    const int lane0 = ((tid & 63) == 0);
    {
        unsigned long long wordA = __ballot(qcA > 0);
        if (lane0) posmask[b * NSTRIP + (jA >> 6)] = wordA;
    }
    if (haveB) {
        unsigned long long wordB = __ballot(qcB > 0);
        if (lane0) posmask[b * NSTRIP + (jB >> 6)] = wordB;
    }

    if (qcA > 0) {
        int gstar = gfA;
        if (qcA > 1) {                         // rare: exact argmax over set bits
            float ib = -1.0f, ub = 1.0f; gstar = 0;
            #pragma unroll
            for (int w = 0; w < 8; ++w) {
                unsigned m = qmA[w];
                while (m) {
                    int t = __ffs(m) - 1; m &= m - 1;
                    int g = w * 32 + t;
                    const float4 gb = gbox[g];
                    float lx = fmaxf(gb.x, pA.x), ly = fmaxf(gb.y, pA.y);
                    float rx = fminf(gb.z, pA.z), ry = fminf(gb.w, pA.w);
                    float ww = fmaxf(rx - lx, 0.0f), hh = fmaxf(ry - ly, 0.0f);
                    float inter = ww * hh;
                    float u = (gar[g] + apA) - inter;
                    // inter/u > ib/ub <=> inter*ub > ib*u ; ascending g +
                    // strict improve == first-max tie rule
                    if (inter * ub > ib * u) { ib = inter; ub = u; gstar = g; }
                }
            }
        }
        posinfo[(size_t)b * NM + jA] = ((unsigned)gstar << 16) | (unsigned)glab[gstar];
    }
    if (haveB && qcB > 0) {
        int gstar = gfB;
        if (qcB > 1) {
            float ib = -1.0f, ub = 1.0f; gstar = 0;
            #pragma unroll
            for (int w = 0; w < 8; ++w) {
                unsigned m = qmB[w];
                while (m) {
                    int t = __ffs(m) - 1; m &= m - 1;
                    int g = w * 32 + t;
                    const float4 gb = gbox[g];
                    float lx = fmaxf(gb.x, pB.x), ly = fmaxf(gb.y, pB.y);
                    float rx = fminf(gb.z, pB.z), ry = fminf(gb.w, pB.w);
                    float ww = fmaxf(rx - lx, 0.0f), hh = fmaxf(ry - ly, 0.0f);
                    float inter = ww * hh;
                    float u = (gar[g] + apB) - inter;
                    if (inter * ub > ib * u) { ib = inter; ub = u; gstar = g; }
                }
            }
        }
        posinfo[(size_t)b * NM + jB] = ((unsigned)gstar << 16) | (unsigned)glab[gstar];
    }
}

// ---------------------------------------------------------------------------
// Kernel 2: per-image balanced sampler (deterministic first-k) + box encoding.
// grid = NB, block = 256. Thread t<254 owns posmask word t; nmask = ~pmask.
// One shfl block-scan (2 barriers), direct-slot writes. Encode only positives.
// ---------------------------------------------------------------------------
__global__ __launch_bounds__(256) void sample_kernel(
    const float4* __restrict__ props4,
    const float4* __restrict__ gt4,
    const float*  __restrict__ gt_thetas,
    const unsigned long long* __restrict__ posmask,
    const unsigned int* __restrict__ posinfo,
    int*   __restrict__ labels_out,   // [NB*NS]
    float* __restrict__ regt_out)     // [NB*NS*5]
{
    __shared__ int sampled[NS];
    __shared__ int wsum[4];

    const int b    = blockIdx.x;
    const int tid  = threadIdx.x;
    const int lane = tid & 63;
    const int wid  = tid >> 6;

    unsigned long long pm = 0ull, nm = 0ull;
    if (tid < NSTRIP) { pm = posmask[b * NSTRIP + tid]; nm = ~pm; }
    int cp = __popcll(pm), cn = __popcll(nm);
    int val  = (cp << 16) | cn;
    int incl = val;
    #pragma unroll
    for (int off = 1; off < 64; off <<= 1) {
        int u = __shfl_up(incl, off, 64);
        if (lane >= off) incl += u;
    }
    if (lane == 63) wsum[wid] = incl;
    __syncthreads();
    int wbase = 0;
    #pragma unroll
    for (int w = 0; w < 4; ++w) if (w < wid) wbase += wsum[w];
    int tot  = wsum[0] + wsum[1] + wsum[2] + wsum[3];
    int excl = wbase + incl - val;
    int rp = excl >> 16, rn = excl & 0xffff;
    int posT = tot >> 16, negT = tot & 0xffff;
    int np = posT < 128 ? posT : 128;          // n_pos = min(pos_total, S/4)
    int nn = NS - np; if (nn > negT) nn = negT;

    const int base = tid * 64;
    if (tid < NSTRIP) {
        #pragma unroll 4
        for (int e = 0; e < 64; ++e) {
            int idx = base + e;
            if ((pm >> e) & 1ull) {
                if (rp < np) sampled[rp + (rn < nn ? rn : nn)] = idx;
                rp++;
            } else {
                if (rn < nn) sampled[rn + (rp < np ? rp : np)] = idx;
                rn++;
            }
        }
    }
    __syncthreads();
    // Fallback fill (unreachable with this data): unselected ascending.
    if (tid == 0 && np + nn < NS) {
        int cpp = 0, cnn = 0, i = np + nn;
        for (int idx = 0; idx < NM && i < NS; ++idx) {
            unsigned long long w = posmask[b * NSTRIP + (idx >> 6)];
            bool p = (w >> (idx & 63)) & 1ull;
            bool sel;
            if (p) { sel = cpp < np; cpp++; } else { sel = cnn < nn; cnn++; }
            if (!sel) sampled[i++] = idx;
        }
    }
    __syncthreads();

    for (int i = tid; i < NS; i += 256) {
        int idx = sampled[i];
        unsigned long long w = posmask[b * NSTRIP + (idx >> 6)];
        bool pos = (w >> (idx & 63)) & 1ull;
        int lbl = 0;
        if (pos) {
            unsigned info = posinfo[(size_t)b * NM + idx];
            int m = info >> 16; lbl = info & 0xffff;
            float4 pv = (idx < NP) ? props4[(size_t)b * NP + idx]
                                   : gt4[(size_t)b * NG + (idx - NP)];
            float4 rv = gt4[(size_t)b * NG + m];
            float pw = pv.z - pv.x, ph = pv.w - pv.y;
            float px = pv.x + 0.5f * pw, py = pv.y + 0.5f * ph;
            float gw = rv.z - rv.x, gh = rv.w - rv.y;
            float gx = rv.x + 0.5f * gw, gy = rv.y + 0.5f * gh;
            float* o = regt_out + ((size_t)b * NS + i) * 5;
            o[0] = 10.0f * (gx - px) / pw;
            o[1] = 10.0f * (gy - py) / ph;
            o[2] = 5.0f * logf(gw / pw);
            o[3] = 5.0f * logf(gh / ph);
            o[4] = gt_thetas[b * NG + m];
        }
        labels_out[b * NS + i] = lbl;
    }
}

// ---------------------------------------------------------------------------
// Kernel 3: fused CE (log-softmax over 91) + smooth-L1 box loss.
// One wave per row, grid-stride; per-block float2 partial (no atomics).
// ---------------------------------------------------------------------------
__global__ __launch_bounds__(256) void loss_kernel(
    const float* __restrict__ logits,     // [N, 91]
    const float* __restrict__ boxreg,     // [N, 455]
    const int*   __restrict__ labels,     // [N]
    const float* __restrict__ regt,       // [N, 5]
    float2* __restrict__ partials)        // [LOSS_BLOCKS]
{
    const int wave  = threadIdx.x >> 6;
    const int lane  = threadIdx.x & 63;
    const int gwave = blockIdx.x * 4 + wave;
    const int NWAVE = LOSS_BLOCKS * 4;
    const int N     = NB * NS;

    float cls_acc = 0.0f, box_acc = 0.0f;

    for (int r = gwave; r < N; r += NWAVE) {
        const float* row = logits + (size_t)r * NCLS;
        float a = (lane < NCLS)      ? row[lane]      : -3.0e38f;
        float c = (lane + 64 < NCLS) ? row[lane + 64] : -3.0e38f;
        float mx = fmaxf(a, c);
        #pragma unroll
        for (int o = 32; o; o >>= 1) mx = fmaxf(mx, __shfl_xor(mx, o, 64));
        float ssum = 0.0f;
        if (lane < NCLS)      ssum += expf(a - mx);
        if (lane + 64 < NCLS) ssum += expf(c - mx);
        #pragma unroll
        for (int o = 32; o; o >>= 1) ssum += __shfl_xor(ssum, o, 64);

        int lab = labels[r];                               // uniform broadcast
        float xl = (lab < 64) ? __shfl(a, lab, 64) : __shfl(c, lab - 64, 64);
        if (lane == 0) cls_acc += -(xl - mx - logf(ssum));

        if (lab > 0) {                                     // uniform branch
            float d = 0.0f;
            if (lane < 5) {
                float pv = boxreg[(size_t)r * (NCLS * 5) + lab * 5 + lane];
                float tv = regt[(size_t)r * 5 + lane];
                d = pv - tv;
            }
            float ad = fabsf(d);
            float sl = (ad < SL1_BETA) ? 0.5f * d * d / SL1_BETA : ad - 0.5f * SL1_BETA;
            sl += __shfl_xor(sl, 4, 8);
            sl += __shfl_xor(sl, 2, 8);
            sl += __shfl_xor(sl, 1, 8);
            if (lane == 0) box_acc += sl;
        }
    }

    __shared__ float cpart[4], bpart[4];
    if (lane == 0) { cpart[wave] = cls_acc; bpart[wave] = box_acc; }
    __syncthreads();
    if (threadIdx.x == 0) {
        partials[blockIdx.x] = make_float2(cpart[0] + cpart[1] + cpart[2] + cpart[3],
                                           bpart[0] + bpart[1] + bpart[2] + bpart[3]);
    }
}

// ---------------------------------------------------------------------------
// Kernel 4: reduce LOSS_BLOCKS float2 partials -> 2 outputs.
// ---------------------------------------------------------------------------
__global__ void final_kernel(const float2* __restrict__ partials,
                             float* __restrict__ out)
{
    const int tid  = threadIdx.x;
    const int lane = tid & 63;
    const int wid  = tid >> 6;
    float2 v0 = partials[tid];
    float2 v1 = partials[tid + 256];
    float c = v0.x + v1.x, bx = v0.y + v1.y;
    #pragma unroll
    for (int o = 32; o; o >>= 1) {
        c  += __shfl_xor(c, o, 64);
        bx += __shfl_xor(bx, o, 64);
    }
    __shared__ float cc[4], bb[4];
    if (lane == 0) { cc[wid] = c; bb[wid] = bx; }
    __syncthreads();
    if (tid == 0) {
        const float invN = 1.0f / (float)(NB * NS);
        out[0] = (cc[0] + cc[1] + cc[2] + cc[3]) * invN;
        out[1] = (bb[0] + bb[1] + bb[2] + bb[3]) * invN;
    }
}

// ---------------------------------------------------------------------------
extern "C" void kernel_launch(void* const* d_in, const int* in_sizes, int n_in,
                              void* d_out, int out_size, void* d_ws, size_t ws_size,
                              hipStream_t stream)
{
    const float* class_logits   = (const float*)d_in[0];  // [NB*NS, 91]
    const float* box_regression = (const float*)d_in[1];  // [NB*NS, 455]
    const float4* props4        = (const float4*)d_in[2]; // [NB, NP]
    const float4* gt4           = (const float4*)d_in[3]; // [NB, NG]
    const float* gt_thetas      = (const float*)d_in[4];  // [NB, NG]
    const int*   gt_labels      = (const int*)d_in[5];    // [NB, NG]
    float* out = (float*)d_out;

    char* ws = (char*)d_ws;
    unsigned long long* posmask = (unsigned long long*)ws;            // NB*NSTRIP u64
    unsigned int* posinfo = (unsigned int*)(ws + ((size_t)NB * NSTRIP * 8 + 255 & ~255ull));
    float2* partials = (float2*)((char*)posinfo + ((size_t)NB * NM * 4 + 255 & ~255ull));
    int* labs   = (int*)((char*)partials + ((LOSS_BLOCKS * sizeof(float2) + 255) & ~255ull));
    float* regt = (float*)(labs + (size_t)NB * NS);

    hipLaunchKernelGGL(match_kernel, dim3(32, NB), dim3(256), 0, stream,
                       props4, gt4, gt_labels, posmask, posinfo);
    hipLaunchKernelGGL(sample_kernel, dim3(NB), dim3(256), 0, stream,
                       props4, gt4, gt_thetas, posmask, posinfo, labs, regt);
    hipLaunchKernelGGL(loss_kernel, dim3(LOSS_BLOCKS), dim3(256), 0, stream,
                       class_logits, box_regression, labs, regt, partials);
    hipLaunchKernelGGL(final_kernel, dim3(1), dim3(256), 0, stream, partials, out);
}

// Round 8
// 54.693 us; speedup vs baseline: 7.1016x; 7.1016x over previous
//
#include <hip/hip_runtime.h>

#define NB 16           // B images
#define NP 16000        // proposals per image
#define NG 256          // gt boxes per image
#define NM (NP + NG)    // proposals + gt = 16256 = 128*127
#define NSTRIP 254      // NM / 64
#define NS 512          // samples per image
#define NCLS 91
#define SL1_BETA (1.0f/9.0f)
#define LOSS_BLOCKS 512

// ---------------------------------------------------------------------------
// Kernel 1 (match): 2 threads per proposal, each owning 128 GTs (half the
// serial chain, 2x the waves: 8128 waves ~ 8/SIMD). Exact qualifier predicate
// iou >= 0.5  <=>  3*inter >= ap+garea (fmaf single-rounding preserves sign).
// Per-thread: qualifier bitmask (4 words, stashed in LDS [256][5]); qcnt==1 ->
// single recompute at that g; qcnt>1 (rare) -> exact cross-product argmax over
// set bits (ascending g). Halves merged via shfl_xor(1): upper half wins only
// on STRICT cross-product improvement (== first-max tie rule, since lower
// half's g are all smaller). Output: packed (gstar<<16)|label per proposal,
// 0 = negative.  grid = (127, NB) x 256.
// ---------------------------------------------------------------------------
__global__ __launch_bounds__(256) void match_kernel(
    const float4* __restrict__ props4,      // [NB*NP]
    const float4* __restrict__ gt4,         // [NB*NG]
    const int*    __restrict__ gt_labels,   // [NB*NG]
    unsigned int* __restrict__ posinfo)     // [NB*NM]
{
    __shared__ float4   gbox[NG];      // 4 KB
    __shared__ float    gar[NG];       // 1 KB
    __shared__ int      glab[NG];      // 1 KB
    __shared__ unsigned qst[256][5];   // 5 KB (stride 5: coprime to 32 banks)

    const int b   = blockIdx.y;
    const int tid = threadIdx.x;

    {   // 256 threads load 256 gts
        const float4 v = gt4[(size_t)b * NG + tid];
        gbox[tid] = v;
        gar[tid]  = (v.z - v.x) * (v.w - v.y);
        glab[tid] = gt_labels[b * NG + tid];
    }
    __syncthreads();

    const int h     = tid & 1;                 // GT half (0: g<128, 1: g>=128)
    const int p     = tid >> 1;                // proposal-in-block 0..127
    const int j     = blockIdx.x * 128 + p;    // < NM always (127*128 = NM)
    const int gbase = h * 128;

    const float4 pb = (j < NP) ? props4[(size_t)b * NP + j]
                               : gt4[(size_t)b * NG + (j - NP)];
    const float ap = (pb.z - pb.x) * (pb.w - pb.y);

    int qcnt = 0, gf = -1;
    for (int w = 0; w < 4; ++w) {
        unsigned m = 0;
        #pragma unroll
        for (int t = 0; t < 32; ++t) {
            const int g = gbase + w * 32 + t;
            const float4 gb = gbox[g];
            const float  ga = gar[g];
            float lx = fmaxf(gb.x, pb.x), ly = fmaxf(gb.y, pb.y);
            float rx = fminf(gb.z, pb.z), ry = fminf(gb.w, pb.w);
            float ww = fmaxf(rx - lx, 0.0f), hh = fmaxf(ry - ly, 0.0f);
            float inter = ww * hh;
            float tt = ga + ap;
            if (fmaf(inter, 3.0f, -tt) >= 0.0f) m |= (1u << t);
        }
        qst[tid][w] = m;
        if (qcnt == 0 && m) gf = w * 32 + (__ffs(m) - 1);
        qcnt += __popc(m);
    }

    // local best (ib/ub = inter/union of best qualifier; needed for the
    // cross-half comparison even when qcnt==1)
    float ib = -1.0f, ub = 1.0f;
    int   gstar = -1;
    if (qcnt == 1) {
        const int g = gbase + gf;
        const float4 gb = gbox[g];
        float lx = fmaxf(gb.x, pb.x), ly = fmaxf(gb.y, pb.y);
        float rx = fminf(gb.z, pb.z), ry = fminf(gb.w, pb.w);
        float ww = fmaxf(rx - lx, 0.0f), hh = fmaxf(ry - ly, 0.0f);
        ib = ww * hh;
        ub = (gar[g] + ap) - ib;
        gstar = g;
    } else if (qcnt > 1) {                     // rare: exact argmax, ascending g
        for (int w = 0; w < 4; ++w) {
            unsigned m = qst[tid][w];
            while (m) {
                int t = __ffs(m) - 1; m &= m - 1;
                int g = gbase + w * 32 + t;
                const float4 gb = gbox[g];
                float lx = fmaxf(gb.x, pb.x), ly = fmaxf(gb.y, pb.y);
                float rx = fminf(gb.z, pb.z), ry = fminf(gb.w, pb.w);
                float ww = fmaxf(rx - lx, 0.0f), hh = fmaxf(ry - ly, 0.0f);
                float inter = ww * hh;
                float u = (gar[g] + ap) - inter;
                // inter/u > ib/ub  <=>  inter*ub > ib*u (u,ub > 0)
                if (inter * ub > ib * u) { ib = inter; ub = u; gstar = g; }
            }
        }
    }

    // merge the two halves (partner lane = lane^1)
    const int   oq  = __shfl_xor(qcnt, 1, 64);
    const float oib = __shfl_xor(ib, 1, 64);
    const float oub = __shfl_xor(ub, 1, 64);
    const int   og  = __shfl_xor(gstar, 1, 64);
    const int qtot = qcnt + oq;
    int gm;
    if (qcnt > 0 && oq > 0) {
        bool otherWins;
        if (h == 0) otherWins = (oib * ub > ib * oub);    // upper strictly better
        else        otherWins = !(ib * oub > oib * ub);   // lower unless self strictly better
        gm = otherWins ? og : gstar;
    } else {
        gm = (qcnt > 0) ? gstar : og;
    }

    if (h == 0) {
        unsigned info = 0;
        if (qtot > 0) info = ((unsigned)gm << 16) | (unsigned)glab[gm];
        posinfo[(size_t)b * NM + j] = info;
    }
}

// ---------------------------------------------------------------------------
// Kernel 2: per-image balanced sampler (deterministic first-k) + box encoding.
// grid = NB, block = 256. Thread t<254 rebuilds its 64-proposal posmask from
// posinfo (info != 0 <=> positive) via uint4 loads; nmask = ~pmask. One shfl
// block-scan (2 barriers), direct-slot writes. Encode only positives.
// ---------------------------------------------------------------------------
__global__ __launch_bounds__(256) void sample_kernel(
    const float4* __restrict__ props4,
    const float4* __restrict__ gt4,
    const float*  __restrict__ gt_thetas,
    const unsigned int* __restrict__ posinfo,
    int*   __restrict__ labels_out,   // [NB*NS]
    float* __restrict__ regt_out)     // [NB*NS*5]
{
    __shared__ int sampled[NS];
    __shared__ int wsum[4];

    const int b    = blockIdx.x;
    const int tid  = threadIdx.x;
    const int lane = tid & 63;
    const int wid  = tid >> 6;
    const unsigned* P = posinfo + (size_t)b * NM;
    const int base = tid * 64;

    unsigned long long pm = 0ull;
    int cn = 0;
    if (tid < NSTRIP) {
        const uint4* Pv = reinterpret_cast<const uint4*>(P + base);
        #pragma unroll
        for (int q = 0; q < 16; ++q) {
            uint4 v = Pv[q];
            int e = q * 4;
            if (v.x) pm |= 1ull << (e + 0);
            if (v.y) pm |= 1ull << (e + 1);
            if (v.z) pm |= 1ull << (e + 2);
            if (v.w) pm |= 1ull << (e + 3);
        }
        cn = 64 - __popcll(pm);
    }
    int cp = (tid < NSTRIP) ? __popcll(pm) : 0;
    int val  = (cp << 16) | cn;
    int incl = val;
    #pragma unroll
    for (int off = 1; off < 64; off <<= 1) {
        int u = __shfl_up(incl, off, 64);
        if (lane >= off) incl += u;
    }
    if (lane == 63) wsum[wid] = incl;
    __syncthreads();
    int wbase = 0;
    #pragma unroll
    for (int w = 0; w < 4; ++w) if (w < wid) wbase += wsum[w];
    int tot  = wsum[0] + wsum[1] + wsum[2] + wsum[3];
    int excl = wbase + incl - val;
    int rp = excl >> 16, rn = excl & 0xffff;
    int posT = tot >> 16, negT = tot & 0xffff;
    int np = posT < 128 ? posT : 128;          // n_pos = min(pos_total, S/4)
    int nn = NS - np; if (nn > negT) nn = negT;

    if (tid < NSTRIP) {
        #pragma unroll 4
        for (int e = 0; e < 64; ++e) {
            int idx = base + e;
            if ((pm >> e) & 1ull) {
                if (rp < np) sampled[rp + (rn < nn ? rn : nn)] = idx;
                rp++;
            } else {
                if (rn < nn) sampled[rn + (rp < np ? rp : np)] = idx;
                rn++;
            }
        }
    }
    __syncthreads();
    // Fallback fill (unreachable with this data): unselected ascending.
    if (tid == 0 && np + nn < NS) {
        int cpp = 0, cnn = 0, i = np + nn;
        for (int idx = 0; idx < NM && i < NS; ++idx) {
            bool p = P[idx] != 0;
            bool sel;
            if (p) { sel = cpp < np; cpp++; } else { sel = cnn < nn; cnn++; }
            if (!sel) sampled[i++] = idx;
        }
    }
    __syncthreads();

    for (int i = tid; i < NS; i += 256) {
        int idx = sampled[i];
        unsigned info = P[idx];
        int lbl = 0;
        if (info) {
            int m = info >> 16; lbl = info & 0xffff;
            float4 pv = (idx < NP) ? props4[(size_t)b * NP + idx]
                                   : gt4[(size_t)b * NG + (idx - NP)];
            float4 rv = gt4[(size_t)b * NG + m];
            float pw = pv.z - pv.x, ph = pv.w - pv.y;
            float px = pv.x + 0.5f * pw, py = pv.y + 0.5f * ph;
            float gw = rv.z - rv.x, gh = rv.w - rv.y;
            float gx = rv.x + 0.5f * gw, gy = rv.y + 0.5f * gh;
            float* o = regt_out + ((size_t)b * NS + i) * 5;
            o[0] = 10.0f * (gx - px) / pw;
            o[1] = 10.0f * (gy - py) / ph;
            o[2] = 5.0f * logf(gw / pw);
            o[3] = 5.0f * logf(gh / ph);
            o[4] = gt_thetas[b * NG + m];
        }
        labels_out[b * NS + i] = lbl;
    }
}

// ---------------------------------------------------------------------------
// Kernel 3: fused CE (log-softmax over 91) + smooth-L1 box loss.
// One wave per row, grid-stride; per-block float2 partial (no atomics).
// ---------------------------------------------------------------------------
__global__ __launch_bounds__(256) void loss_kernel(
    const float* __restrict__ logits,     // [N, 91]
    const float* __restrict__ boxreg,     // [N, 455]
    const int*   __restrict__ labels,     // [N]
    const float* __restrict__ regt,       // [N, 5]
    float2* __restrict__ partials)        // [LOSS_BLOCKS]
{
    const int wave  = threadIdx.x >> 6;
    const int lane  = threadIdx.x & 63;
    const int gwave = blockIdx.x * 4 + wave;
    const int NWAVE = LOSS_BLOCKS * 4;
    const int N     = NB * NS;

    float cls_acc = 0.0f, box_acc = 0.0f;

    for (int r = gwave; r < N; r += NWAVE) {
        const float* row = logits + (size_t)r * NCLS;
        float a = (lane < NCLS)      ? row[lane]      : -3.0e38f;
        float c = (lane + 64 < NCLS) ? row[lane + 64] : -3.0e38f;
        float mx = fmaxf(a, c);
        #pragma unroll
        for (int o = 32; o; o >>= 1) mx = fmaxf(mx, __shfl_xor(mx, o, 64));
        float ssum = 0.0f;
        if (lane < NCLS)      ssum += expf(a - mx);
        if (lane + 64 < NCLS) ssum += expf(c - mx);
        #pragma unroll
        for (int o = 32; o; o >>= 1) ssum += __shfl_xor(ssum, o, 64);

        int lab = labels[r];                               // uniform broadcast
        float xl = (lab < 64) ? __shfl(a, lab, 64) : __shfl(c, lab - 64, 64);
        if (lane == 0) cls_acc += -(xl - mx - logf(ssum));

        if (lab > 0) {                                     // uniform branch
            float d = 0.0f;
            if (lane < 5) {
                float pv = boxreg[(size_t)r * (NCLS * 5) + lab * 5 + lane];
                float tv = regt[(size_t)r * 5 + lane];
                d = pv - tv;
            }
            float ad = fabsf(d);
            float sl = (ad < SL1_BETA) ? 0.5f * d * d / SL1_BETA : ad - 0.5f * SL1_BETA;
            sl += __shfl_xor(sl, 4, 8);
            sl += __shfl_xor(sl, 2, 8);
            sl += __shfl_xor(sl, 1, 8);
            if (lane == 0) box_acc += sl;
        }
    }

    __shared__ float cpart[4], bpart[4];
    if (lane == 0) { cpart[wave] = cls_acc; bpart[wave] = box_acc; }
    __syncthreads();
    if (threadIdx.x == 0) {
        partials[blockIdx.x] = make_float2(cpart[0] + cpart[1] + cpart[2] + cpart[3],
                                           bpart[0] + bpart[1] + bpart[2] + bpart[3]);
    }
}

// ---------------------------------------------------------------------------
// Kernel 4: reduce LOSS_BLOCKS float2 partials -> 2 outputs.
// ---------------------------------------------------------------------------
__global__ void final_kernel(const float2* __restrict__ partials,
                             float* __restrict__ out)
{
    const int tid  = threadIdx.x;
    const int lane = tid & 63;
    const int wid  = tid >> 6;
    float2 v0 = partials[tid];
    float2 v1 = partials[tid + 256];
    float c = v0.x + v1.x, bx = v0.y + v1.y;
    #pragma unroll
    for (int o = 32; o; o >>= 1) {
        c  += __shfl_xor(c, o, 64);
        bx += __shfl_xor(bx, o, 64);
    }
    __shared__ float cc[4], bb[4];
    if (lane == 0) { cc[wid] = c; bb[wid] = bx; }
    __syncthreads();
    if (tid == 0) {
        const float invN = 1.0f / (float)(NB * NS);
        out[0] = (cc[0] + cc[1] + cc[2] + cc[3]) * invN;
        out[1] = (bb[0] + bb[1] + bb[2] + bb[3]) * invN;
    }
}

// ---------------------------------------------------------------------------
extern "C" void kernel_launch(void* const* d_in, const int* in_sizes, int n_in,
                              void* d_out, int out_size, void* d_ws, size_t ws_size,
                              hipStream_t stream)
{
    const float* class_logits   = (const float*)d_in[0];  // [NB*NS, 91]
    const float* box_regression = (const float*)d_in[1];  // [NB*NS, 455]
    const float4* props4        = (const float4*)d_in[2]; // [NB, NP]
    const float4* gt4           = (const float4*)d_in[3]; // [NB, NG]
    const float* gt_thetas      = (const float*)d_in[4];  // [NB, NG]
    const int*   gt_labels      = (const int*)d_in[5];    // [NB, NG]
    float* out = (float*)d_out;

    char* ws = (char*)d_ws;
    unsigned int* posinfo = (unsigned int*)ws;                        // NB*NM u32
    float2* partials = (float2*)(ws + (((size_t)NB * NM * 4 + 255) & ~255ull));
    int* labs   = (int*)((char*)partials + ((LOSS_BLOCKS * sizeof(float2) + 255) & ~255ull));
    float* regt = (float*)(labs + (size_t)NB * NS);

    hipLaunchKernelGGL(match_kernel, dim3(127, NB), dim3(256), 0, stream,
                       props4, gt4, gt_labels, posinfo);
    hipLaunchKernelGGL(sample_kernel, dim3(NB), dim3(256), 0, stream,
                       props4, gt4, gt_thetas, posinfo, labs, regt);
    hipLaunchKernelGGL(loss_kernel, dim3(LOSS_BLOCKS), dim3(256), 0, stream,
                       class_logits, box_regression, labs, regt, partials);
    hipLaunchKernelGGL(final_kernel, dim3(1), dim3(256), 0, stream, partials, out);
}